// Round 1
// baseline (258.707 us; speedup 1.0000x reference)
//
#include <hip/hip_runtime.h>

// Problem constants (from reference setup_inputs): B=16384, D_in=512, H=512
#define M_ROWS 16384
#define N_COLS 1536   // 3*H
#define K_DIM  512
#define H_DIM  512

typedef __attribute__((ext_vector_type(8))) short short8;  // 8 bf16 = 4 VGPRs
typedef __attribute__((ext_vector_type(4))) float f32x4;

__device__ __forceinline__ unsigned short f2bf(float f) {
  unsigned u = __float_as_uint(f);
  u += 0x7fffu + ((u >> 16) & 1u);   // RNE
  return (unsigned short)(u >> 16);
}
__device__ __forceinline__ float bf2f(unsigned short h) {
  return __uint_as_float(((unsigned)h) << 16);
}

__device__ __forceinline__ void gload_lds16(const void* g, void* l) {
  __builtin_amdgcn_global_load_lds((const __attribute__((address_space(1))) void*)g,
                                   (__attribute__((address_space(3))) void*)l,
                                   16, 0, 0);
}

// ---------------- fp32 -> bf16 convert ----------------
__global__ void cvt_f32_bf16(const float* __restrict__ src,
                             unsigned short* __restrict__ dst, int n4) {
  int i = blockIdx.x * blockDim.x + threadIdx.x;
  if (i < n4) {
    float4 f = ((const float4*)src)[i];
    ushort4 u;
    u.x = f2bf(f.x); u.y = f2bf(f.y); u.z = f2bf(f.z); u.w = f2bf(f.w);
    ((ushort4*)dst)[i] = u;
  }
}

// ---------------- GEMM (bf16 MFMA) + bias + per-row LN stats ----------------
// C[m][n] = sum_k A[m][k] * W[n][k] + bias[n]   (W stored [N][K] row-major == B^T GEMM)
// blockIdx.z selects (x, W_i2h, b_i2h, xt) vs (hx, W_h2h, b_h2h, ht).
// Tile: BM=128, BN=128, BK=64; 4 waves in 2x2, each wave 64x64 via 4x4 MFMA 16x16x32 tiles.
// stats layout: ((mat*2+sec)*2+kind)*M_ROWS + row, kind 0=sum 1=sumsq, sec: cols [0,1024) / [1024,1536)
__global__ __launch_bounds__(256) void gemm_ln_stats(
    const unsigned short* __restrict__ xb, const unsigned short* __restrict__ hxb,
    const unsigned short* __restrict__ Wib, const unsigned short* __restrict__ Whb,
    const float* __restrict__ b_i2h, const float* __restrict__ b_h2h,
    unsigned short* __restrict__ xt, unsigned short* __restrict__ ht,
    float* __restrict__ stats) {
  const int mat = blockIdx.z;
  const unsigned short* A  = mat ? hxb : xb;
  const unsigned short* Bw = mat ? Whb : Wib;
  const float* bias        = mat ? b_h2h : b_i2h;
  unsigned short* outp     = mat ? ht : xt;

  const int m0 = blockIdx.x * 128;
  const int n0 = blockIdx.y * 128;

  __shared__ short lds[2 * 128 * 64];  // A tile then B tile, 32 KiB
  short* ldsA = lds;
  short* ldsB = lds + 128 * 64;

  const int t = threadIdx.x;
  const int w = t >> 6, lane = t & 63;
  const int w_row = w >> 1, w_col = w & 1;
  const int lane15 = lane & 15, quad = lane >> 4;

  f32x4 acc[4][4];
#pragma unroll
  for (int i = 0; i < 4; ++i)
#pragma unroll
    for (int j = 0; j < 4; ++j) acc[i][j] = (f32x4){0.f, 0.f, 0.f, 0.f};

  const int srow = lane >> 3;        // 0..7 within an 8-row wave segment
  const int scol = (lane & 7) * 8;   // element col (8 bf16 = 16 B per lane)

  for (int k0 = 0; k0 < K_DIM; k0 += 64) {
#pragma unroll
    for (int q = 0; q < 4; ++q) {
      const int base_row = w * 32 + q * 8;
      gload_lds16(A  + (size_t)(m0 + base_row + srow) * K_DIM + k0 + scol,
                  &ldsA[base_row * 64]);
      gload_lds16(Bw + (size_t)(n0 + base_row + srow) * K_DIM + k0 + scol,
                  &ldsB[base_row * 64]);
    }
    __syncthreads();  // drains vmcnt -> staging complete
#pragma unroll
    for (int kk = 0; kk < 2; ++kk) {
      short8 af[4], bf[4];
#pragma unroll
      for (int i = 0; i < 4; ++i)
        af[i] = *(const short8*)&ldsA[(w_row * 64 + i * 16 + lane15) * 64 + kk * 32 + quad * 8];
#pragma unroll
      for (int j = 0; j < 4; ++j)
        bf[j] = *(const short8*)&ldsB[(w_col * 64 + j * 16 + lane15) * 64 + kk * 32 + quad * 8];
#pragma unroll
      for (int i = 0; i < 4; ++i)
#pragma unroll
        for (int j = 0; j < 4; ++j)
          acc[i][j] = __builtin_amdgcn_mfma_f32_16x16x32_bf16(af[i], bf[j], acc[i][j], 0, 0, 0);
    }
    __syncthreads();  // all waves done reading before next overwrite
  }

  // Epilogue: bias, bf16 store, per-row sum/sumsq (computed on the ROUNDED
  // values so finalize's LN is self-consistent with what it reads back).
  const int sec = (n0 >= 1024) ? 1 : 0;
  float* sumA = stats + (size_t)((mat * 2 + sec) * 2 + 0) * M_ROWS;
  float* sqA  = stats + (size_t)((mat * 2 + sec) * 2 + 1) * M_ROWS;

  float bj[4];
#pragma unroll
  for (int j = 0; j < 4; ++j) bj[j] = bias[n0 + w_col * 64 + j * 16 + lane15];

#pragma unroll
  for (int i = 0; i < 4; ++i) {
#pragma unroll
    for (int r = 0; r < 4; ++r) {
      const int rowl = w_row * 64 + i * 16 + quad * 4 + r;  // C/D: row = quad*4+reg
      const int grow = m0 + rowl;
      unsigned short* orow = outp + (size_t)grow * N_COLS + n0 + w_col * 64 + lane15;
      float s = 0.f, s2 = 0.f;
#pragma unroll
      for (int j = 0; j < 4; ++j) {
        float v = acc[i][j][r] + bj[j];
        unsigned short hv = f2bf(v);
        orow[j * 16] = hv;                 // col = lane&15 within each 16-wide tile
        float vf = bf2f(hv);
        s += vf; s2 += vf * vf;
      }
      // reduce across the 16 lanes of this quad (cols) -> row totals
#pragma unroll
      for (int msk = 1; msk < 16; msk <<= 1) {
        s  += __shfl_xor(s, msk);
        s2 += __shfl_xor(s2, msk);
      }
      if (lane15 == 0) {
        atomicAdd(&sumA[grow], s);
        atomicAdd(&sqA[grow], s2);
      }
    }
  }
}

// ---------------- finalize: LN + gates + GRU blend ----------------
__global__ __launch_bounds__(256) void finalize_kernel(
    const unsigned short* __restrict__ xt, const unsigned short* __restrict__ ht,
    const float* __restrict__ hx, const float* __restrict__ stats,
    float* __restrict__ out) {
  const int b = blockIdx.x;
  const int t = threadIdx.x;
  const float inv2H = 1.f / 1024.f, invH = 1.f / 512.f;

  const float mx0 = stats[(size_t)0 * M_ROWS + b] * inv2H;
  const float ix0 = rsqrtf(stats[(size_t)1 * M_ROWS + b] * inv2H - mx0 * mx0 + 1e-5f);
  const float mx1 = stats[(size_t)2 * M_ROWS + b] * invH;
  const float ix1 = rsqrtf(stats[(size_t)3 * M_ROWS + b] * invH - mx1 * mx1 + 1e-5f);
  const float mh0 = stats[(size_t)4 * M_ROWS + b] * inv2H;
  const float ih0 = rsqrtf(stats[(size_t)5 * M_ROWS + b] * inv2H - mh0 * mh0 + 1e-5f);
  const float mh1 = stats[(size_t)6 * M_ROWS + b] * invH;
  const float ih1 = rsqrtf(stats[(size_t)7 * M_ROWS + b] * invH - mh1 * mh1 + 1e-5f);

  const int j = t * 2;
  const size_t rowx = (size_t)b * N_COLS;
  ushort2 xr = *(const ushort2*)&xt[rowx + j];
  ushort2 xz = *(const ushort2*)&xt[rowx + 512 + j];
  ushort2 xn = *(const ushort2*)&xt[rowx + 1024 + j];
  ushort2 hr = *(const ushort2*)&ht[rowx + j];
  ushort2 hz = *(const ushort2*)&ht[rowx + 512 + j];
  ushort2 hn = *(const ushort2*)&ht[rowx + 1024 + j];
  float2 hxv = *(const float2*)&hx[(size_t)b * H_DIM + j];

  auto calc = [&](unsigned short uxr, unsigned short uxz, unsigned short uxn,
                  unsigned short uhr, unsigned short uhz, unsigned short uhn,
                  float hxs) -> float {
    float ar = (bf2f(uxr) - mx0) * ix0 + (bf2f(uhr) - mh0) * ih0;
    float az = (bf2f(uxz) - mx0) * ix0 + (bf2f(uhz) - mh0) * ih0;
    float r = 1.f / (1.f + expf(-ar));
    float z = 1.f / (1.f + expf(-az));
    float nn = tanhf((bf2f(uxn) - mx1) * ix1 + r * ((bf2f(uhn) - mh1) * ih1));
    return z * hxs + (1.f - z) * nn;
  };
  float2 res;
  res.x = calc(xr.x, xz.x, xn.x, hr.x, hz.x, hn.x, hxv.x);
  res.y = calc(xr.y, xz.y, xn.y, hr.y, hz.y, hn.y, hxv.y);
  *(float2*)&out[(size_t)b * H_DIM + j] = res;
}

// ---------------- launch ----------------
// Workspace layout (bytes):            offset        size
//   xb  (bf16 x,  16384x512)               0      16777216
//   hxb (bf16 hx, 16384x512)        16777216      16777216
//   Wib (bf16,  1536x512)           33554432       1572864
//   Whb (bf16,  1536x512)           35127296       1572864
//   xt  (bf16, 16384x1536)          36700160      50331648
//   ht  (bf16, 16384x1536)          87031808      50331648
//   stats (fp32, 8*16384)          137363456        524288
// total ~131.5 MiB
extern "C" void kernel_launch(void* const* d_in, const int* in_sizes, int n_in,
                              void* d_out, int out_size, void* d_ws, size_t ws_size,
                              hipStream_t stream) {
  const float* x  = (const float*)d_in[0];
  const float* hx = (const float*)d_in[1];
  const float* Wi = (const float*)d_in[2];
  const float* bi = (const float*)d_in[3];
  const float* Wh = (const float*)d_in[4];
  const float* bh = (const float*)d_in[5];
  float* out = (float*)d_out;

  char* ws = (char*)d_ws;
  unsigned short* xb  = (unsigned short*)(ws);
  unsigned short* hxb = (unsigned short*)(ws + 16777216);
  unsigned short* Wib = (unsigned short*)(ws + 33554432);
  unsigned short* Whb = (unsigned short*)(ws + 35127296);
  unsigned short* xt  = (unsigned short*)(ws + 36700160);
  unsigned short* ht  = (unsigned short*)(ws + 87031808);
  float* stats        = (float*)(ws + 137363456);

  const int xq = M_ROWS * K_DIM / 4;   // 2097152
  const int wq = N_COLS * K_DIM / 4;   // 196608
  cvt_f32_bf16<<<(xq + 255) / 256, 256, 0, stream>>>(x, xb, xq);
  cvt_f32_bf16<<<(xq + 255) / 256, 256, 0, stream>>>(hx, hxb, xq);
  cvt_f32_bf16<<<(wq + 255) / 256, 256, 0, stream>>>(Wi, Wib, wq);
  cvt_f32_bf16<<<(wq + 255) / 256, 256, 0, stream>>>(Wh, Whb, wq);
  hipMemsetAsync(stats, 0, (size_t)8 * M_ROWS * 4, stream);  // memset node: graph-capturable

  gemm_ln_stats<<<dim3(M_ROWS / 128, N_COLS / 128, 2), 256, 0, stream>>>(
      xb, hxb, Wib, Whb, bi, bh, xt, ht, stats);

  finalize_kernel<<<M_ROWS, 256, 0, stream>>>(xt, ht, hx, stats, out);
}

// Round 2
// 235.558 us; speedup vs baseline: 1.0983x; 1.0983x over previous
//
#include <hip/hip_runtime.h>

// Problem constants: B=16384, D_in=512, H=512
#define M_ROWS 16384
#define N_COLS 1536   // 3*H
#define K_DIM  512
#define H_DIM  512

typedef __attribute__((ext_vector_type(8))) short short8;  // 8 bf16 = 4 VGPRs
typedef __attribute__((ext_vector_type(4))) float f32x4;

__device__ __forceinline__ unsigned short f2bf(float f) {
  unsigned u = __float_as_uint(f);
  u += 0x7fffu + ((u >> 16) & 1u);   // RNE
  return (unsigned short)(u >> 16);
}
__device__ __forceinline__ float bf2f(unsigned short h) {
  return __uint_as_float(((unsigned)h) << 16);
}

__device__ __forceinline__ void gload_lds16(const void* g, void* l) {
  __builtin_amdgcn_global_load_lds((const __attribute__((address_space(1))) void*)g,
                                   (__attribute__((address_space(3))) void*)l,
                                   16, 0, 0);
}

// ---------------- fp32 -> bf16 convert, all 4 buffers in one launch ----------
// segment sizes in float4 units: x 2097152 | hx 2097152 | Wi 196608 | Wh 196608
__global__ __launch_bounds__(256) void cvt_all(
    const float* __restrict__ x, const float* __restrict__ hx,
    const float* __restrict__ Wi, const float* __restrict__ Wh,
    unsigned short* __restrict__ xb, unsigned short* __restrict__ hxb,
    unsigned short* __restrict__ Wib, unsigned short* __restrict__ Whb) {
  int i = blockIdx.x * blockDim.x + threadIdx.x;   // grid exactly 4587520 threads
  const float* s; unsigned short* d; int off;
  if (i < 2097152)      { s = x;  d = xb;  off = i; }
  else if (i < 4194304) { s = hx; d = hxb; off = i - 2097152; }
  else if (i < 4390912) { s = Wi; d = Wib; off = i - 4194304; }
  else                  { s = Wh; d = Whb; off = i - 4390912; }
  float4 f = ((const float4*)s)[off];
  ushort4 u;
  u.x = f2bf(f.x); u.y = f2bf(f.y); u.z = f2bf(f.z); u.w = f2bf(f.w);
  ((ushort4*)d)[off] = u;
}

// ---------------- GEMM (bf16 MFMA) + bias, permuted packed store ------------
// C[m][n] = sum_k A[m][k]*W[n][k] + bias[n].  blockIdx.z: 0=(x,Wi,bi,xt) 1=(hx,Wh,bh,ht)
// Tile BM=BN=128, BK=64; 4 waves 2x2; wave does 64x64 via 4x4 of 16x16x32 MFMA.
// LDS XOR swizzle: 16B chunk c of row r stored at physical chunk c^(r&7).
// Output store permutation within each 64-col block: value for true col
// 16*j+lane15 stored at slot 4*lane15+j, i.e. true = 16*(s&3)+(s>>2).
__global__ __launch_bounds__(256) void gemm_bf16(
    const unsigned short* __restrict__ xb, const unsigned short* __restrict__ hxb,
    const unsigned short* __restrict__ Wib, const unsigned short* __restrict__ Whb,
    const float* __restrict__ b_i2h, const float* __restrict__ b_h2h,
    unsigned short* __restrict__ xt, unsigned short* __restrict__ ht) {
  const int mat = blockIdx.z;
  const unsigned short* A  = mat ? hxb : xb;
  const unsigned short* Bw = mat ? Whb : Wib;
  const float* bias        = mat ? b_h2h : b_i2h;
  unsigned short* outp     = mat ? ht : xt;

  const int m0 = blockIdx.x * 128;
  const int n0 = blockIdx.y * 128;

  __shared__ short lds[2 * 128 * 64];  // A tile then B tile, 32 KiB
  short* ldsA = lds;
  short* ldsB = lds + 128 * 64;

  const int t = threadIdx.x;
  const int w = t >> 6, lane = t & 63;
  const int w_row = w >> 1, w_col = w & 1;
  const int lane15 = lane & 15, quad = lane >> 4;

  f32x4 acc[4][4];
#pragma unroll
  for (int i = 0; i < 4; ++i)
#pragma unroll
    for (int j = 0; j < 4; ++j) acc[i][j] = (f32x4){0.f, 0.f, 0.f, 0.f};

  const int srow = lane >> 3;                       // 0..7 row within 8-row seg
  const int scol = ((lane & 7) ^ srow) * 8;         // XOR-swizzled source chunk

  for (int k0 = 0; k0 < K_DIM; k0 += 64) {
#pragma unroll
    for (int q = 0; q < 4; ++q) {
      const int base_row = w * 32 + q * 8;
      gload_lds16(A  + (size_t)(m0 + base_row + srow) * K_DIM + k0 + scol,
                  &ldsA[base_row * 64]);
      gload_lds16(Bw + (size_t)(n0 + base_row + srow) * K_DIM + k0 + scol,
                  &ldsB[base_row * 64]);
    }
    __syncthreads();
#pragma unroll
    for (int kk = 0; kk < 2; ++kk) {
      short8 af[4], bf[4];
      const int l7 = lane15 & 7;
#pragma unroll
      for (int i = 0; i < 4; ++i)
        af[i] = *(const short8*)&ldsA[(w_row * 64 + i * 16 + lane15) * 64 +
                                      (((kk * 4 + quad) ^ l7) * 8)];
#pragma unroll
      for (int j = 0; j < 4; ++j)
        bf[j] = *(const short8*)&ldsB[(w_col * 64 + j * 16 + lane15) * 64 +
                                      (((kk * 4 + quad) ^ l7) * 8)];
#pragma unroll
      for (int i = 0; i < 4; ++i)
#pragma unroll
        for (int j = 0; j < 4; ++j)
          acc[i][j] = __builtin_amdgcn_mfma_f32_16x16x32_bf16(af[i], bf[j], acc[i][j], 0, 0, 0);
    }
    __syncthreads();
  }

  // Epilogue: bias + packed permuted bf16 store (16x dwordx2 per lane).
  float bj[4];
#pragma unroll
  for (int j = 0; j < 4; ++j) bj[j] = bias[n0 + w_col * 64 + j * 16 + lane15];

#pragma unroll
  for (int i = 0; i < 4; ++i) {
#pragma unroll
    for (int r = 0; r < 4; ++r) {
      const int rowl = w_row * 64 + i * 16 + quad * 4 + r;  // C/D row = quad*4+reg
      ushort4 pk;
      pk.x = f2bf(acc[i][0][r] + bj[0]);
      pk.y = f2bf(acc[i][1][r] + bj[1]);
      pk.z = f2bf(acc[i][2][r] + bj[2]);
      pk.w = f2bf(acc[i][3][r] + bj[3]);
      *(ushort4*)(outp + (size_t)(m0 + rowl) * N_COLS + n0 + w_col * 64 + lane15 * 4) = pk;
    }
  }
}

// ---------------- finalize: row stats + LN + gates + GRU blend --------------
// Reads the permuted xt/ht rows, block-reduces LN stats, inverts the column
// permutation for hx/out indexing: true col = (p>>6)*64 + 16*(s&3) + (s>>2).
__global__ __launch_bounds__(256) void finalize_kernel(
    const unsigned short* __restrict__ xt, const unsigned short* __restrict__ ht,
    const float* __restrict__ hx, float* __restrict__ out) {
  const int b = blockIdx.x;
  const int t = threadIdx.x;
  const size_t rb = (size_t)b * N_COLS;
  const int p = 2 * t;

  ushort2 xr = *(const ushort2*)&xt[rb + p];
  ushort2 xz = *(const ushort2*)&xt[rb + 512 + p];
  ushort2 xn = *(const ushort2*)&xt[rb + 1024 + p];
  ushort2 hr = *(const ushort2*)&ht[rb + p];
  ushort2 hz = *(const ushort2*)&ht[rb + 512 + p];
  ushort2 hn = *(const ushort2*)&ht[rb + 1024 + p];

  float vxr0 = bf2f(xr.x), vxr1 = bf2f(xr.y);
  float vxz0 = bf2f(xz.x), vxz1 = bf2f(xz.y);
  float vxn0 = bf2f(xn.x), vxn1 = bf2f(xn.y);
  float vhr0 = bf2f(hr.x), vhr1 = bf2f(hr.y);
  float vhz0 = bf2f(hz.x), vhz1 = bf2f(hz.y);
  float vhn0 = bf2f(hn.x), vhn1 = bf2f(hn.y);

  float pr[8];
  pr[0] = vxr0 + vxr1 + vxz0 + vxz1;
  pr[1] = vxr0 * vxr0 + vxr1 * vxr1 + vxz0 * vxz0 + vxz1 * vxz1;
  pr[2] = vxn0 + vxn1;
  pr[3] = vxn0 * vxn0 + vxn1 * vxn1;
  pr[4] = vhr0 + vhr1 + vhz0 + vhz1;
  pr[5] = vhr0 * vhr0 + vhr1 * vhr1 + vhz0 * vhz0 + vhz1 * vhz1;
  pr[6] = vhn0 + vhn1;
  pr[7] = vhn0 * vhn0 + vhn1 * vhn1;

#pragma unroll
  for (int msk = 1; msk < 64; msk <<= 1)
#pragma unroll
    for (int k = 0; k < 8; ++k) pr[k] += __shfl_xor(pr[k], msk);

  __shared__ float red[4][8];
  const int w = t >> 6, lane = t & 63;
  if (lane == 0)
#pragma unroll
    for (int k = 0; k < 8; ++k) red[w][k] = pr[k];
  __syncthreads();
  float tot[8];
#pragma unroll
  for (int k = 0; k < 8; ++k)
    tot[k] = red[0][k] + red[1][k] + red[2][k] + red[3][k];

  const float inv2H = 1.f / 1024.f, invH = 1.f / 512.f;
  const float mx0 = tot[0] * inv2H;
  const float ix0 = rsqrtf(tot[1] * inv2H - mx0 * mx0 + 1e-5f);
  const float mx1 = tot[2] * invH;
  const float ix1 = rsqrtf(tot[3] * invH - mx1 * mx1 + 1e-5f);
  const float mh0 = tot[4] * inv2H;
  const float ih0 = rsqrtf(tot[5] * inv2H - mh0 * mh0 + 1e-5f);
  const float mh1 = tot[6] * invH;
  const float ih1 = rsqrtf(tot[7] * invH - mh1 * mh1 + 1e-5f);

  // invert store permutation: stored slot s within 64-block -> true col
  const int s0 = p & 63, blk = p >> 6;
  const int c0 = blk * 64 + 16 * (s0 & 3) + (s0 >> 2);
  const int s1 = s0 + 1;
  const int c1 = blk * 64 + 16 * (s1 & 3) + (s1 >> 2);

  auto calc = [&](float xrv, float xzv, float xnv, float hrv, float hzv,
                  float hnv, float hxs) -> float {
    float ar = (xrv - mx0) * ix0 + (hrv - mh0) * ih0;
    float az = (xzv - mx0) * ix0 + (hzv - mh0) * ih0;
    float r = 1.f / (1.f + __expf(-ar));
    float z = 1.f / (1.f + __expf(-az));
    float arg = (xnv - mx1) * ix1 + r * ((hnv - mh1) * ih1);
    float e2 = __expf(2.f * arg);
    float nn = (e2 - 1.f) / (e2 + 1.f);
    return z * hxs + (1.f - z) * nn;
  };

  const float* hxrow = hx + (size_t)b * H_DIM;
  float* orow = out + (size_t)b * H_DIM;
  orow[c0] = calc(vxr0, vxz0, vxn0, vhr0, vhz0, vhn0, hxrow[c0]);
  orow[c1] = calc(vxr1, vxz1, vxn1, vhr1, vhz1, vhn1, hxrow[c1]);
}

// ---------------- launch ----------------
// Workspace layout (bytes):            offset        size
//   xb  (bf16 x,  16384x512)               0      16777216
//   hxb (bf16 hx, 16384x512)        16777216      16777216
//   Wib (bf16,  1536x512)           33554432       1572864
//   Whb (bf16,  1536x512)           35127296       1572864
//   xt  (bf16, 16384x1536, permuted) 36700160     50331648
//   ht  (bf16, 16384x1536, permuted) 87031808     50331648
// total ~131 MiB
extern "C" void kernel_launch(void* const* d_in, const int* in_sizes, int n_in,
                              void* d_out, int out_size, void* d_ws, size_t ws_size,
                              hipStream_t stream) {
  const float* x  = (const float*)d_in[0];
  const float* hx = (const float*)d_in[1];
  const float* Wi = (const float*)d_in[2];
  const float* bi = (const float*)d_in[3];
  const float* Wh = (const float*)d_in[4];
  const float* bh = (const float*)d_in[5];
  float* out = (float*)d_out;

  char* ws = (char*)d_ws;
  unsigned short* xb  = (unsigned short*)(ws);
  unsigned short* hxb = (unsigned short*)(ws + 16777216);
  unsigned short* Wib = (unsigned short*)(ws + 33554432);
  unsigned short* Whb = (unsigned short*)(ws + 35127296);
  unsigned short* xt  = (unsigned short*)(ws + 36700160);
  unsigned short* ht  = (unsigned short*)(ws + 87031808);

  cvt_all<<<17920, 256, 0, stream>>>(x, hx, Wi, Wh, xb, hxb, Wib, Whb);

  gemm_bf16<<<dim3(M_ROWS / 128, N_COLS / 128, 2), 256, 0, stream>>>(
      xb, hxb, Wib, Whb, bi, bh, xt, ht);

  finalize_kernel<<<M_ROWS, 256, 0, stream>>>(xt, ht, hx, out);
}

// Round 3
// 206.784 us; speedup vs baseline: 1.2511x; 1.1392x over previous
//
#include <hip/hip_runtime.h>

// Problem constants: B=16384, D_in=512, H=512
#define M_ROWS 16384
#define N_COLS 1536   // 3*H
#define K_DIM  512
#define H_DIM  512

typedef __attribute__((ext_vector_type(8))) short short8;  // 8 bf16 = 4 VGPRs
typedef __attribute__((ext_vector_type(4))) float f32x4;

__device__ __forceinline__ unsigned short f2bf(float f) {
  unsigned u = __float_as_uint(f);
  u += 0x7fffu + ((u >> 16) & 1u);   // RNE
  return (unsigned short)(u >> 16);
}
__device__ __forceinline__ float bf2f(unsigned short h) {
  return __uint_as_float(((unsigned)h) << 16);
}

__device__ __forceinline__ void gload_lds16(const void* g, void* l) {
  __builtin_amdgcn_global_load_lds((const __attribute__((address_space(1))) void*)g,
                                   (__attribute__((address_space(3))) void*)l,
                                   16, 0, 0);
}

// ---------------- fp32 -> bf16 convert, all 4 buffers in one launch ----------
// segment sizes in float4 units: x 2097152 | hx 2097152 | Wi 196608 | Wh 196608
__global__ __launch_bounds__(256) void cvt_all(
    const float* __restrict__ x, const float* __restrict__ hx,
    const float* __restrict__ Wi, const float* __restrict__ Wh,
    unsigned short* __restrict__ xb, unsigned short* __restrict__ hxb,
    unsigned short* __restrict__ Wib, unsigned short* __restrict__ Whb) {
  int i = blockIdx.x * blockDim.x + threadIdx.x;   // grid exactly 4587520 threads
  const float* s; unsigned short* d; int off;
  if (i < 2097152)      { s = x;  d = xb;  off = i; }
  else if (i < 4194304) { s = hx; d = hxb; off = i - 2097152; }
  else if (i < 4390912) { s = Wi; d = Wib; off = i - 4194304; }
  else                  { s = Wh; d = Whb; off = i - 4390912; }
  float4 f = ((const float4*)s)[off];
  ushort4 u;
  u.x = f2bf(f.x); u.y = f2bf(f.y); u.z = f2bf(f.z); u.w = f2bf(f.w);
  ((ushort4*)d)[off] = u;
}

// ---------------- GEMM (bf16 MFMA) + bias, permuted packed store ------------
// C[m][n] = sum_k A[m][k]*W[n][k] + bias[n].  blockIdx.z: 0=(x,Wi,bi,xt) 1=(hx,Wh,bh,ht)
// Tile BM=BN=128, BK=64; 4 waves 2x2; wave does 64x64 via 4x4 of 16x16x32 MFMA.
// LDS XOR swizzle: 16B chunk c of row r stored at physical chunk c^(r&7).
// Output store permutation within each aligned 64-col block: value for true col
// 16*j+lane15 stored at slot 4*lane15+j, i.e. true = 16*(s&3)+(s>>2).
__global__ __launch_bounds__(256) void gemm_bf16(
    const unsigned short* __restrict__ xb, const unsigned short* __restrict__ hxb,
    const unsigned short* __restrict__ Wib, const unsigned short* __restrict__ Whb,
    const float* __restrict__ b_i2h, const float* __restrict__ b_h2h,
    unsigned short* __restrict__ xt, unsigned short* __restrict__ ht) {
  const int mat = blockIdx.z;
  const unsigned short* A  = mat ? hxb : xb;
  const unsigned short* Bw = mat ? Whb : Wib;
  const float* bias        = mat ? b_h2h : b_i2h;
  unsigned short* outp     = mat ? ht : xt;

  const int m0 = blockIdx.x * 128;
  const int n0 = blockIdx.y * 128;

  __shared__ short lds[2 * 128 * 64];  // A tile then B tile, 32 KiB
  short* ldsA = lds;
  short* ldsB = lds + 128 * 64;

  const int t = threadIdx.x;
  const int w = t >> 6, lane = t & 63;
  const int w_row = w >> 1, w_col = w & 1;
  const int lane15 = lane & 15, quad = lane >> 4;

  f32x4 acc[4][4];
#pragma unroll
  for (int i = 0; i < 4; ++i)
#pragma unroll
    for (int j = 0; j < 4; ++j) acc[i][j] = (f32x4){0.f, 0.f, 0.f, 0.f};

  const int srow = lane >> 3;                       // 0..7 row within 8-row seg
  const int scol = ((lane & 7) ^ srow) * 8;         // XOR-swizzled source chunk

  for (int k0 = 0; k0 < K_DIM; k0 += 64) {
#pragma unroll
    for (int q = 0; q < 4; ++q) {
      const int base_row = w * 32 + q * 8;
      gload_lds16(A  + (size_t)(m0 + base_row + srow) * K_DIM + k0 + scol,
                  &ldsA[base_row * 64]);
      gload_lds16(Bw + (size_t)(n0 + base_row + srow) * K_DIM + k0 + scol,
                  &ldsB[base_row * 64]);
    }
    __syncthreads();
#pragma unroll
    for (int kk = 0; kk < 2; ++kk) {
      short8 af[4], bf[4];
      const int l7 = lane15 & 7;
#pragma unroll
      for (int i = 0; i < 4; ++i)
        af[i] = *(const short8*)&ldsA[(w_row * 64 + i * 16 + lane15) * 64 +
                                      (((kk * 4 + quad) ^ l7) * 8)];
#pragma unroll
      for (int j = 0; j < 4; ++j)
        bf[j] = *(const short8*)&ldsB[(w_col * 64 + j * 16 + lane15) * 64 +
                                      (((kk * 4 + quad) ^ l7) * 8)];
#pragma unroll
      for (int i = 0; i < 4; ++i)
#pragma unroll
        for (int j = 0; j < 4; ++j)
          acc[i][j] = __builtin_amdgcn_mfma_f32_16x16x32_bf16(af[i], bf[j], acc[i][j], 0, 0, 0);
    }
    __syncthreads();
  }

  // Epilogue: bias + packed permuted bf16 store (16x dwordx2 per lane).
  float bj[4];
#pragma unroll
  for (int j = 0; j < 4; ++j) bj[j] = bias[n0 + w_col * 64 + j * 16 + lane15];

#pragma unroll
  for (int i = 0; i < 4; ++i) {
#pragma unroll
    for (int r = 0; r < 4; ++r) {
      const int rowl = w_row * 64 + i * 16 + quad * 4 + r;  // C/D row = quad*4+reg
      ushort4 pk;
      pk.x = f2bf(acc[i][0][r] + bj[0]);
      pk.y = f2bf(acc[i][1][r] + bj[1]);
      pk.z = f2bf(acc[i][2][r] + bj[2]);
      pk.w = f2bf(acc[i][3][r] + bj[3]);
      *(ushort4*)(outp + (size_t)(m0 + rowl) * N_COLS + n0 + w_col * 64 + lane15 * 4) = pk;
    }
  }
}

// ---------------- finalize: wave-per-row, b128 loads, float2 hx/out ---------
// Permuted slot s (within aligned 64-block) holds true col 16*(s&3)+(s>>2).
// Lane l reads slots 8l..8l+7 of each 512-wide section -> true cols
// 64*(l>>3) + 16*j + 2*(l&7) + {0,1} for j=0..3 (pairs: value k=j and k=j+4).
__global__ __launch_bounds__(256) void finalize_kernel(
    const unsigned short* __restrict__ xt, const unsigned short* __restrict__ ht,
    const float* __restrict__ hx, float* __restrict__ out) {
  const int w = threadIdx.x >> 6, lane = threadIdx.x & 63;
  const int b = blockIdx.x * 4 + w;            // one row per wave
  const size_t rb = (size_t)b * N_COLS;
  const int la = lane & 7, lb = lane >> 3;

  short8 sxr = *(const short8*)&xt[rb + 8 * lane];
  short8 sxz = *(const short8*)&xt[rb + 512 + 8 * lane];
  short8 sxn = *(const short8*)&xt[rb + 1024 + 8 * lane];
  short8 shr = *(const short8*)&ht[rb + 8 * lane];
  short8 shz = *(const short8*)&ht[rb + 512 + 8 * lane];
  short8 shn = *(const short8*)&ht[rb + 1024 + 8 * lane];

  float vxr[8], vxz[8], vxn[8], vhr[8], vhz[8], vhn[8];
#pragma unroll
  for (int k = 0; k < 8; ++k) {
    vxr[k] = bf2f((unsigned short)sxr[k]);
    vxz[k] = bf2f((unsigned short)sxz[k]);
    vxn[k] = bf2f((unsigned short)sxn[k]);
    vhr[k] = bf2f((unsigned short)shr[k]);
    vhz[k] = bf2f((unsigned short)shz[k]);
    vhn[k] = bf2f((unsigned short)shn[k]);
  }

  float pr[8] = {0.f, 0.f, 0.f, 0.f, 0.f, 0.f, 0.f, 0.f};
#pragma unroll
  for (int k = 0; k < 8; ++k) {
    pr[0] += vxr[k] + vxz[k];
    pr[1] += vxr[k] * vxr[k] + vxz[k] * vxz[k];
    pr[2] += vxn[k];
    pr[3] += vxn[k] * vxn[k];
    pr[4] += vhr[k] + vhz[k];
    pr[5] += vhr[k] * vhr[k] + vhz[k] * vhz[k];
    pr[6] += vhn[k];
    pr[7] += vhn[k] * vhn[k];
  }
#pragma unroll
  for (int msk = 1; msk < 64; msk <<= 1)
#pragma unroll
    for (int k = 0; k < 8; ++k) pr[k] += __shfl_xor(pr[k], msk);

  const float inv2H = 1.f / 1024.f, invH = 1.f / 512.f;
  const float mx0 = pr[0] * inv2H;
  const float ix0 = rsqrtf(pr[1] * inv2H - mx0 * mx0 + 1e-5f);
  const float mx1 = pr[2] * invH;
  const float ix1 = rsqrtf(pr[3] * invH - mx1 * mx1 + 1e-5f);
  const float mh0 = pr[4] * inv2H;
  const float ih0 = rsqrtf(pr[5] * inv2H - mh0 * mh0 + 1e-5f);
  const float mh1 = pr[6] * invH;
  const float ih1 = rsqrtf(pr[7] * invH - mh1 * mh1 + 1e-5f);

  auto calc = [&](float xrv, float xzv, float xnv, float hrv, float hzv,
                  float hnv, float hxs) -> float {
    float ar = (xrv - mx0) * ix0 + (hrv - mh0) * ih0;
    float az = (xzv - mx0) * ix0 + (hzv - mh0) * ih0;
    float r = 1.f / (1.f + __expf(-ar));
    float z = 1.f / (1.f + __expf(-az));
    float arg = (xnv - mx1) * ix1 + r * ((hnv - mh1) * ih1);
    float e2 = __expf(2.f * arg);
    float nn = (e2 - 1.f) / (e2 + 1.f);
    return z * hxs + (1.f - z) * nn;
  };

  const float* hxrow = hx + (size_t)b * H_DIM;
  float* orow = out + (size_t)b * H_DIM;
#pragma unroll
  for (int j = 0; j < 4; ++j) {
    const int col = lb * 64 + j * 16 + 2 * la;
    float2 hxv = *(const float2*)&hxrow[col];
    float2 res;
    res.x = calc(vxr[j], vxz[j], vxn[j], vhr[j], vhz[j], vhn[j], hxv.x);
    res.y = calc(vxr[j + 4], vxz[j + 4], vxn[j + 4], vhr[j + 4], vhz[j + 4],
                 vhn[j + 4], hxv.y);
    *(float2*)&orow[col] = res;
  }
}

// ---------------- launch ----------------
// Workspace layout (bytes):            offset        size
//   xb  (bf16 x,  16384x512)               0      16777216
//   hxb (bf16 hx, 16384x512)        16777216      16777216
//   Wib (bf16,  1536x512)           33554432       1572864
//   Whb (bf16,  1536x512)           35127296       1572864
//   xt  (bf16, 16384x1536, permuted) 36700160     50331648
//   ht  (bf16, 16384x1536, permuted) 87031808     50331648
// total ~131 MiB
extern "C" void kernel_launch(void* const* d_in, const int* in_sizes, int n_in,
                              void* d_out, int out_size, void* d_ws, size_t ws_size,
                              hipStream_t stream) {
  const float* x  = (const float*)d_in[0];
  const float* hx = (const float*)d_in[1];
  const float* Wi = (const float*)d_in[2];
  const float* bi = (const float*)d_in[3];
  const float* Wh = (const float*)d_in[4];
  const float* bh = (const float*)d_in[5];
  float* out = (float*)d_out;

  char* ws = (char*)d_ws;
  unsigned short* xb  = (unsigned short*)(ws);
  unsigned short* hxb = (unsigned short*)(ws + 16777216);
  unsigned short* Wib = (unsigned short*)(ws + 33554432);
  unsigned short* Whb = (unsigned short*)(ws + 35127296);
  unsigned short* xt  = (unsigned short*)(ws + 36700160);
  unsigned short* ht  = (unsigned short*)(ws + 87031808);

  cvt_all<<<17920, 256, 0, stream>>>(x, hx, Wi, Wh, xb, hxb, Wib, Whb);

  gemm_bf16<<<dim3(M_ROWS / 128, N_COLS / 128, 2), 256, 0, stream>>>(
      xb, hxb, Wib, Whb, bi, bh, xt, ht);

  finalize_kernel<<<M_ROWS / 4, 256, 0, stream>>>(xt, ht, hx, out);
}

// Round 4
// 202.477 us; speedup vs baseline: 1.2777x; 1.0213x over previous
//
#include <hip/hip_runtime.h>

// Problem constants: B=16384, D_in=512, H=512
#define M_ROWS 16384
#define N_COLS 1536   // 3*H
#define K_DIM  512
#define H_DIM  512

typedef __attribute__((ext_vector_type(8))) short short8;   // 8 bf16 = 4 VGPRs
typedef __attribute__((ext_vector_type(16))) float f32x16;  // 32x32 MFMA acc

__device__ __forceinline__ unsigned short f2bf(float f) {
  unsigned u = __float_as_uint(f);
  u += 0x7fffu + ((u >> 16) & 1u);   // RNE
  return (unsigned short)(u >> 16);
}
__device__ __forceinline__ float bf2f(unsigned short h) {
  return __uint_as_float(((unsigned)h) << 16);
}

__device__ __forceinline__ void gload_lds16(const void* g, void* l) {
  __builtin_amdgcn_global_load_lds((const __attribute__((address_space(1))) void*)g,
                                   (__attribute__((address_space(3))) void*)l,
                                   16, 0, 0);
}

// ---------------- fp32 -> bf16 convert, all 4 buffers in one launch ----------
__global__ __launch_bounds__(256) void cvt_all(
    const float* __restrict__ x, const float* __restrict__ hx,
    const float* __restrict__ Wi, const float* __restrict__ Wh,
    unsigned short* __restrict__ xb, unsigned short* __restrict__ hxb,
    unsigned short* __restrict__ Wib, unsigned short* __restrict__ Whb) {
  int i = blockIdx.x * blockDim.x + threadIdx.x;   // grid exactly 4587520 threads
  const float* s; unsigned short* d; int off;
  if (i < 2097152)      { s = x;  d = xb;  off = i; }
  else if (i < 4194304) { s = hx; d = hxb; off = i - 2097152; }
  else if (i < 4390912) { s = Wi; d = Wib; off = i - 4194304; }
  else                  { s = Wh; d = Whb; off = i - 4390912; }
  float4 f = ((const float4*)s)[off];
  ushort4 u;
  u.x = f2bf(f.x); u.y = f2bf(f.y); u.z = f2bf(f.z); u.w = f2bf(f.w);
  ((ushort4*)d)[off] = u;
}

// ---------------- GEMM (bf16 MFMA 32x32x16) + bias, permuted store ----------
// C[m][n] = sum_k A[m][k]*W[n][k] + bias[n].  blockIdx.z: 0=(x,Wi,bi,xt) 1=(hx,Wh,bh,ht)
// Tile BM=BN=128, BK=64; 4 waves 2x2; wave does 64x64 via 2x2 of 32x32x16 MFMA.
// LDS XOR swizzle: 16B chunk c of row r stored at physical chunk c^(r&7).
// Store permutation within each aligned 64-col group: value for true col
// 32*j + c (c=lane&31, j=0..1) stored at slot 2c+j, i.e. true = 32*(s&1)+(s>>1).
__global__ __launch_bounds__(256, 4) void gemm_bf16(
    const unsigned short* __restrict__ xb, const unsigned short* __restrict__ hxb,
    const unsigned short* __restrict__ Wib, const unsigned short* __restrict__ Whb,
    const float* __restrict__ b_i2h, const float* __restrict__ b_h2h,
    unsigned short* __restrict__ xt, unsigned short* __restrict__ ht) {
  const int mat = blockIdx.z;
  const unsigned short* A  = mat ? hxb : xb;
  const unsigned short* Bw = mat ? Whb : Wib;
  const float* bias        = mat ? b_h2h : b_i2h;
  unsigned short* outp     = mat ? ht : xt;

  const int m0 = blockIdx.x * 128;
  const int n0 = blockIdx.y * 128;

  __shared__ short lds[2 * 128 * 64];  // A tile then B tile, 32 KiB
  short* ldsA = lds;
  short* ldsB = lds + 128 * 64;

  const int t = threadIdx.x;
  const int w = t >> 6, lane = t & 63;
  const int w_row = w >> 1, w_col = w & 1;
  const int l31 = lane & 31, h = lane >> 5;

  f32x16 acc[2][2];
#pragma unroll
  for (int i = 0; i < 2; ++i)
#pragma unroll
    for (int j = 0; j < 2; ++j)
#pragma unroll
      for (int r = 0; r < 16; ++r) acc[i][j][r] = 0.f;

  const int srow = lane >> 3;                       // 0..7 row within 8-row seg
  const int scol = ((lane & 7) ^ srow) * 8;         // XOR-swizzled source chunk

  for (int k0 = 0; k0 < K_DIM; k0 += 64) {
#pragma unroll
    for (int q = 0; q < 4; ++q) {
      const int base_row = w * 32 + q * 8;
      gload_lds16(A  + (size_t)(m0 + base_row + srow) * K_DIM + k0 + scol,
                  &ldsA[base_row * 64]);
      gload_lds16(Bw + (size_t)(n0 + base_row + srow) * K_DIM + k0 + scol,
                  &ldsB[base_row * 64]);
    }
    __syncthreads();
#pragma unroll
    for (int kk = 0; kk < 4; ++kk) {
      // lane needs A[m=l31][k = kk*16 + h*8 + j] -> logical chunk kk*2+h,
      // physical chunk (kk*2+h) ^ (l31&7)
      const int chunk = ((kk * 2 + h) ^ (l31 & 7)) * 8;
      short8 af[2], bf[2];
#pragma unroll
      for (int i = 0; i < 2; ++i)
        af[i] = *(const short8*)&ldsA[(w_row * 64 + i * 32 + l31) * 64 + chunk];
#pragma unroll
      for (int j = 0; j < 2; ++j)
        bf[j] = *(const short8*)&ldsB[(w_col * 64 + j * 32 + l31) * 64 + chunk];
#pragma unroll
      for (int i = 0; i < 2; ++i)
#pragma unroll
        for (int j = 0; j < 2; ++j)
          acc[i][j] = __builtin_amdgcn_mfma_f32_32x32x16_bf16(af[i], bf[j], acc[i][j], 0, 0, 0);
    }
    __syncthreads();
  }

  // Epilogue: bias + packed permuted ushort2 store.
  // C/D: col=l31, row=(reg&3)+8*(reg>>2)+4*h
  float bj0[2], bj1[2];
#pragma unroll
  for (int j = 0; j < 2; ++j) {
    bj0[j] = bias[n0 + w_col * 64 + 0 * 32 + l31] * 0.f;  // placeholder (unused)
  }
  const float biasj0 = bias[n0 + w_col * 64 + l31];
  const float biasj1 = bias[n0 + w_col * 64 + 32 + l31];

#pragma unroll
  for (int i = 0; i < 2; ++i) {
#pragma unroll
    for (int g = 0; g < 4; ++g) {
#pragma unroll
      for (int d = 0; d < 4; ++d) {
        const int reg = g * 4 + d;
        const int row = d + 8 * g + 4 * h;
        ushort2 pk;
        pk.x = f2bf(acc[i][0][reg] + biasj0);
        pk.y = f2bf(acc[i][1][reg] + biasj1);
        *(ushort2*)(outp + (size_t)(m0 + w_row * 64 + i * 32 + row) * N_COLS +
                    n0 + w_col * 64 + 2 * l31) = pk;
      }
    }
  }
}

// ---------------- finalize: wave-per-row, b128 loads, float4 hx/out ---------
// Permuted slot s (within aligned 64-group) holds true col 32*(s&1)+(s>>1).
// Lane l reads slots 8l..8l+7 of each 512-wide section: group = l>>3,
// e=0..7 -> true col 64*(l>>3) + 32*(e&1) + 4*(l&7) + (e>>1).
// So even e cover cols base4..base4+3, odd e cover base4+32..base4+35,
// base4 = 64*(l>>3) + 4*(l&7)  -> float4-shaped hx/out access.
__global__ __launch_bounds__(256) void finalize_kernel(
    const unsigned short* __restrict__ xt, const unsigned short* __restrict__ ht,
    const unsigned short* __restrict__ hxb, float* __restrict__ out) {
  const int w = threadIdx.x >> 6, lane = threadIdx.x & 63;
  const int b = blockIdx.x * 4 + w;            // one row per wave
  const size_t rb = (size_t)b * N_COLS;

  short8 sxr = *(const short8*)&xt[rb + 8 * lane];
  short8 sxz = *(const short8*)&xt[rb + 512 + 8 * lane];
  short8 sxn = *(const short8*)&xt[rb + 1024 + 8 * lane];
  short8 shr = *(const short8*)&ht[rb + 8 * lane];
  short8 shz = *(const short8*)&ht[rb + 512 + 8 * lane];
  short8 shn = *(const short8*)&ht[rb + 1024 + 8 * lane];

  float vxr[8], vxz[8], vxn[8], vhr[8], vhz[8], vhn[8];
#pragma unroll
  for (int k = 0; k < 8; ++k) {
    vxr[k] = bf2f((unsigned short)sxr[k]);
    vxz[k] = bf2f((unsigned short)sxz[k]);
    vxn[k] = bf2f((unsigned short)sxn[k]);
    vhr[k] = bf2f((unsigned short)shr[k]);
    vhz[k] = bf2f((unsigned short)shz[k]);
    vhn[k] = bf2f((unsigned short)shn[k]);
  }

  float pr[8] = {0.f, 0.f, 0.f, 0.f, 0.f, 0.f, 0.f, 0.f};
#pragma unroll
  for (int k = 0; k < 8; ++k) {
    pr[0] += vxr[k] + vxz[k];
    pr[1] += vxr[k] * vxr[k] + vxz[k] * vxz[k];
    pr[2] += vxn[k];
    pr[3] += vxn[k] * vxn[k];
    pr[4] += vhr[k] + vhz[k];
    pr[5] += vhr[k] * vhr[k] + vhz[k] * vhz[k];
    pr[6] += vhn[k];
    pr[7] += vhn[k] * vhn[k];
  }
#pragma unroll
  for (int msk = 1; msk < 64; msk <<= 1)
#pragma unroll
    for (int k = 0; k < 8; ++k) pr[k] += __shfl_xor(pr[k], msk);

  const float inv2H = 1.f / 1024.f, invH = 1.f / 512.f;
  const float mx0 = pr[0] * inv2H;
  const float ix0 = rsqrtf(pr[1] * inv2H - mx0 * mx0 + 1e-5f);
  const float mx1 = pr[2] * invH;
  const float ix1 = rsqrtf(pr[3] * invH - mx1 * mx1 + 1e-5f);
  const float mh0 = pr[4] * inv2H;
  const float ih0 = rsqrtf(pr[5] * inv2H - mh0 * mh0 + 1e-5f);
  const float mh1 = pr[6] * invH;
  const float ih1 = rsqrtf(pr[7] * invH - mh1 * mh1 + 1e-5f);

  auto calc = [&](float xrv, float xzv, float xnv, float hrv, float hzv,
                  float hnv, float hxs) -> float {
    float ar = (xrv - mx0) * ix0 + (hrv - mh0) * ih0;
    float az = (xzv - mx0) * ix0 + (hzv - mh0) * ih0;
    float r = 1.f / (1.f + __expf(-ar));
    float z = 1.f / (1.f + __expf(-az));
    float arg = (xnv - mx1) * ix1 + r * ((hnv - mh1) * ih1);
    float e2 = __expf(2.f * arg);
    float nn = (e2 - 1.f) / (e2 + 1.f);
    return z * hxs + (1.f - z) * nn;
  };

  const int base4 = 64 * (lane >> 3) + 4 * (lane & 7);
  const unsigned short* hxrow = hxb + (size_t)b * H_DIM;
  float* orow = out + (size_t)b * H_DIM;

  ushort4 hx0u = *(const ushort4*)&hxrow[base4];
  ushort4 hx1u = *(const ushort4*)&hxrow[base4 + 32];
  float hx0[4] = {bf2f(hx0u.x), bf2f(hx0u.y), bf2f(hx0u.z), bf2f(hx0u.w)};
  float hx1[4] = {bf2f(hx1u.x), bf2f(hx1u.y), bf2f(hx1u.z), bf2f(hx1u.w)};

  float4 r0, r1;
  float* r0p = (float*)&r0;
  float* r1p = (float*)&r1;
#pragma unroll
  for (int k = 0; k < 4; ++k) {
    r0p[k] = calc(vxr[2 * k], vxz[2 * k], vxn[2 * k],
                  vhr[2 * k], vhz[2 * k], vhn[2 * k], hx0[k]);
    r1p[k] = calc(vxr[2 * k + 1], vxz[2 * k + 1], vxn[2 * k + 1],
                  vhr[2 * k + 1], vhz[2 * k + 1], vhn[2 * k + 1], hx1[k]);
  }
  *(float4*)&orow[base4] = r0;
  *(float4*)&orow[base4 + 32] = r1;
}

// ---------------- launch ----------------
// Workspace layout (bytes):            offset        size
//   xb  (bf16 x,  16384x512)               0      16777216
//   hxb (bf16 hx, 16384x512)        16777216      16777216
//   Wib (bf16,  1536x512)           33554432       1572864
//   Whb (bf16,  1536x512)           35127296       1572864
//   xt  (bf16, 16384x1536, permuted) 36700160     50331648
//   ht  (bf16, 16384x1536, permuted) 87031808     50331648
extern "C" void kernel_launch(void* const* d_in, const int* in_sizes, int n_in,
                              void* d_out, int out_size, void* d_ws, size_t ws_size,
                              hipStream_t stream) {
  const float* x  = (const float*)d_in[0];
  const float* hx = (const float*)d_in[1];
  const float* Wi = (const float*)d_in[2];
  const float* bi = (const float*)d_in[3];
  const float* Wh = (const float*)d_in[4];
  const float* bh = (const float*)d_in[5];
  float* out = (float*)d_out;

  char* ws = (char*)d_ws;
  unsigned short* xb  = (unsigned short*)(ws);
  unsigned short* hxb = (unsigned short*)(ws + 16777216);
  unsigned short* Wib = (unsigned short*)(ws + 33554432);
  unsigned short* Whb = (unsigned short*)(ws + 35127296);
  unsigned short* xt  = (unsigned short*)(ws + 36700160);
  unsigned short* ht  = (unsigned short*)(ws + 87031808);

  cvt_all<<<17920, 256, 0, stream>>>(x, hx, Wi, Wh, xb, hxb, Wib, Whb);

  gemm_bf16<<<dim3(M_ROWS / 128, N_COLS / 128, 2), 256, 0, stream>>>(
      xb, hxb, Wib, Whb, bi, bh, xt, ht);

  finalize_kernel<<<M_ROWS / 4, 256, 0, stream>>>(xt, ht, hxb, out);
}